// Round 2
// baseline (181.099 us; speedup 1.0000x reference)
//
#include <hip/hip_runtime.h>
#include <math.h>

// Problem constants (fixed shapes from reference)
#define B_ 2
#define N_ 16384
#define M_ 12000
#define F_ 16384

// knn kernel config
#define VPT_ 8                // vertices per thread
#define CHUNK_ (256 * VPT_)   // 2048 vertices per block
#define NCHUNK_ (N_ / CHUNK_) // 8 chunks per batch

// ---------------------------------------------------------------------------
// Kernel A: per-face precompute.
//   fcurr[f] = (centroid_curr.xyz, |centroid_curr|^2)
//   fnext[2f] = (centroid_next.xyz, 0), fnext[2f+1] = (unit_normal.xyz, 0)
// ---------------------------------------------------------------------------
__global__ __launch_bounds__(256) void face_precomp(
    const float* __restrict__ obs_curr,
    const float* __restrict__ obs_next,
    const int* __restrict__ faces,
    float4* __restrict__ fcurr,
    float4* __restrict__ fnext) {
  int t = blockIdx.x * 256 + threadIdx.x;
  if (t >= B_ * F_) return;
  int b = t / F_;
  const float* oc = obs_curr + (size_t)b * M_ * 3;
  const float* on = obs_next + (size_t)b * M_ * 3;
  int i0 = faces[3 * (size_t)t + 0];
  int i1 = faces[3 * (size_t)t + 1];
  int i2 = faces[3 * (size_t)t + 2];

  // current centroid
  float ax = oc[3*i0], ay = oc[3*i0+1], az = oc[3*i0+2];
  float bx = oc[3*i1], by = oc[3*i1+1], bz = oc[3*i1+2];
  float cx = oc[3*i2], cy = oc[3*i2+1], cz = oc[3*i2+2];
  float gx = (ax + bx + cx) / 3.0f;
  float gy = (ay + by + cy) / 3.0f;
  float gz = (az + bz + cz) / 3.0f;
  fcurr[t] = make_float4(gx, gy, gz, gx*gx + gy*gy + gz*gz);

  // next centroid + normal
  float nax = on[3*i0], nay = on[3*i0+1], naz = on[3*i0+2];
  float nbx = on[3*i1], nby = on[3*i1+1], nbz = on[3*i1+2];
  float ncx = on[3*i2], ncy = on[3*i2+1], ncz = on[3*i2+2];
  float hx = (nax + nbx + ncx) / 3.0f;
  float hy = (nay + nby + ncy) / 3.0f;
  float hz = (naz + nbz + ncz) / 3.0f;
  float e1x = nbx - nax, e1y = nby - nay, e1z = nbz - naz;
  float e2x = ncx - nax, e2y = ncy - nay, e2z = ncz - naz;
  float crx = e1y * e2z - e1z * e2y;
  float cry = e1z * e2x - e1x * e2z;
  float crz = e1x * e2y - e1y * e2x;
  float len = sqrtf(crx*crx + cry*cry + crz*crz);
  float inv = 1.0f / (len + 1e-12f);
  fnext[2 * (size_t)t + 0] = make_float4(hx, hy, hz, 0.0f);
  fnext[2 * (size_t)t + 1] = make_float4(crx*inv, cry*inv, crz*inv, 0.0f);
}

// ---------------------------------------------------------------------------
// Kernel B: brute-force argmin over faces (partitioned into P tiles).
//   score = |fc|^2 - 2*c.fc  (argmin-equivalent to d2). 8 vertices/thread
//   amortize each LDS face read across 8 pairs.
//   __launch_bounds__(256,4): cap 128 VGPR (need ~60) — avoid the 32-VGPR
//   clamp+spill seen in round 1 (VGPR_Count=32 with ~48 live values).
// ---------------------------------------------------------------------------
template <int P>
__global__ __launch_bounds__(256, 4) void knn_argmin(
    const float* __restrict__ cloth_curr,
    const float4* __restrict__ fcurr,
    float2* __restrict__ partial) {
  constexpr int TILE = F_ / P;
  __shared__ float4 tile[TILE];
  int bid = blockIdx.x;             // [0, B*NCHUNK*P)
  int p = bid % P;                  // face partition
  int chunk = (bid / P) % NCHUNK_;  // vertex chunk
  int b = bid / (P * NCHUNK_);      // batch

  int vbase = chunk * CHUNK_ + threadIdx.x;
  float m2x[VPT_], m2y[VPT_], m2z[VPT_];
#pragma unroll
  for (int v = 0; v < VPT_; ++v) {
    int i = vbase + v * 256;
    const float* cp = cloth_curr + ((size_t)b * N_ + i) * 3;
    m2x[v] = -2.0f * cp[0];
    m2y[v] = -2.0f * cp[1];
    m2z[v] = -2.0f * cp[2];
  }

  const float4* src = fcurr + (size_t)b * F_ + (size_t)p * TILE;
  for (int k = threadIdx.x; k < TILE; k += 256) tile[k] = src[k];
  __syncthreads();

  float best[VPT_];
  int bidx[VPT_];
#pragma unroll
  for (int v = 0; v < VPT_; ++v) { best[v] = 3.4e38f; bidx[v] = 0; }

#pragma unroll 4
  for (int f = 0; f < TILE; ++f) {
    float4 fc = tile[f];
#pragma unroll
    for (int v = 0; v < VPT_; ++v) {
      float s = fmaf(m2x[v], fc.x, fmaf(m2y[v], fc.y, fmaf(m2z[v], fc.z, fc.w)));
      bool m = s < best[v];
      best[v] = m ? s : best[v];
      bidx[v] = m ? f : bidx[v];
    }
  }

  int fbase = p * TILE;
#pragma unroll
  for (int v = 0; v < VPT_; ++v) {
    int i = vbase + v * 256;
    partial[((size_t)(b * P + p)) * N_ + i] =
        make_float2(best[v], __int_as_float(bidx[v] + fbase));
  }
}

// ---------------------------------------------------------------------------
// Kernel C: reduce partitions, gather face-next data, plane distance,
// interpenetration, weight; write per_vert and per-block loss partials.
// ---------------------------------------------------------------------------
template <int P>
__global__ __launch_bounds__(256) void epilogue(
    const float* __restrict__ cloth_next,
    const float4* __restrict__ fnext,
    const float2* __restrict__ partial,
    const int* __restrict__ iter_num,
    float* __restrict__ out,
    float* __restrict__ block_sums) {
  int i = blockIdx.x * 256 + threadIdx.x;  // vertex [0, N)

  // weight ramp (double to match Python scalar math)
  int it = *iter_num;
  double itc = (double)(it - 50000);
  if (itc < 0.0) itc = 0.0;
  double prog = itc / 100000.0;
  if (prog > 1.0) prog = 1.0;
  float weight = (float)(1e-3 + (5e3 - 1e-3) * prog);
  float scale = weight * 0.5f;  // weight / B

  float acc = 0.0f;
#pragma unroll
  for (int b = 0; b < B_; ++b) {
    float best = 3.4e38f;
    int bidx = 0;
#pragma unroll
    for (int p = 0; p < P; ++p) {
      float2 pv = partial[((size_t)(b * P + p)) * N_ + i];
      bool m = pv.x < best;
      best = m ? pv.x : best;
      bidx = m ? __float_as_int(pv.y) : bidx;
    }
    float4 cent = fnext[2 * ((size_t)b * F_ + bidx) + 0];
    float4 nrm  = fnext[2 * ((size_t)b * F_ + bidx) + 1];
    const float* np2 = cloth_next + ((size_t)b * N_ + i) * 3;
    float dist = (np2[0] - cent.x) * nrm.x +
                 (np2[1] - cent.y) * nrm.y +
                 (np2[2] - cent.z) * nrm.z;
    float ip = fmaxf(1e-3f - dist, 0.0f);
    acc += ip * ip * ip;
  }
  acc *= scale;
  out[1 + i] = acc;  // per_vert

  // block-level loss partial (deterministic: no atomics)
  float r = acc;
  for (int off = 32; off > 0; off >>= 1) r += __shfl_down(r, off, 64);
  __shared__ float wsum[4];
  int lane = threadIdx.x & 63;
  int w = threadIdx.x >> 6;
  if (lane == 0) wsum[w] = r;
  __syncthreads();
  if (threadIdx.x == 0)
    block_sums[blockIdx.x] = wsum[0] + wsum[1] + wsum[2] + wsum[3];
}

__global__ void final_sum(const float* __restrict__ block_sums,
                          float* __restrict__ out) {
  float v = block_sums[threadIdx.x];  // 64 threads, 64 partials
  for (int off = 32; off > 0; off >>= 1) v += __shfl_down(v, off, 64);
  if (threadIdx.x == 0) out[0] = v;
}

// ---------------------------------------------------------------------------
extern "C" void kernel_launch(void* const* d_in, const int* in_sizes, int n_in,
                              void* d_out, int out_size, void* d_ws, size_t ws_size,
                              hipStream_t stream) {
  const float* cloth_curr = (const float*)d_in[0];
  const float* cloth_next = (const float*)d_in[1];
  const float* obs_curr   = (const float*)d_in[2];
  const float* obs_next   = (const float*)d_in[3];
  const int*   faces      = (const int*)d_in[4];
  const int*   iter_num   = (const int*)d_in[5];
  float* out = (float*)d_out;

  // workspace layout (all 16B-aligned)
  char* w = (char*)d_ws;
  float4* fcurr   = (float4*)(w);                 // B*F   float4 = 512 KB
  float4* fnext   = (float4*)(w + 524288);        // B*F*2 float4 = 1 MB
  float2* partial = (float2*)(w + 1572864);       // B*P*N float2

  face_precomp<<<(B_ * F_ + 255) / 256, 256, 0, stream>>>(
      obs_curr, obs_next, faces, fcurr, fnext);

  // P=64 needs 1.5MB + 16MB + block_sums; fall back to P=32 on small ws.
  if (ws_size >= (size_t)20 * 1024 * 1024) {
    constexpr int P = 64;
    float* block_sums = (float*)(w + 1572864 + (size_t)B_ * P * N_ * 8);
    knn_argmin<P><<<B_ * NCHUNK_ * P, 256, 0, stream>>>(
        cloth_curr, fcurr, partial);
    epilogue<P><<<N_ / 256, 256, 0, stream>>>(
        cloth_next, fnext, partial, iter_num, out, block_sums);
    final_sum<<<1, 64, 0, stream>>>(block_sums, out);
  } else {
    constexpr int P = 32;
    float* block_sums = (float*)(w + 1572864 + (size_t)B_ * P * N_ * 8);
    knn_argmin<P><<<B_ * NCHUNK_ * P, 256, 0, stream>>>(
        cloth_curr, fcurr, partial);
    epilogue<P><<<N_ / 256, 256, 0, stream>>>(
        cloth_next, fnext, partial, iter_num, out, block_sums);
    final_sum<<<1, 64, 0, stream>>>(block_sums, out);
  }
}

// Round 3
// 137.700 us; speedup vs baseline: 1.3152x; 1.3152x over previous
//
#include <hip/hip_runtime.h>
#include <math.h>

// Problem constants (fixed shapes from reference)
#define B_ 2
#define N_ 16384
#define M_ 12000
#define F_ 16384

// knn kernel config
#define P_ 128                // face partitions
#define TILE_ (F_ / P_)       // 128 faces per LDS tile
#define VPT_ 8                // vertices per thread
#define CHUNK_ (256 * VPT_)   // 2048 vertices per block
#define NCHUNK_ (N_ / CHUNK_) // 8 chunks per batch

// ---------------------------------------------------------------------------
// Kernel A: per-face precompute.
//   fcurr[f] = (centroid_curr.xyz, |centroid_curr|^2)
//   fnext[2f] = (centroid_next.xyz, 0), fnext[2f+1] = (unit_normal.xyz, 0)
// ---------------------------------------------------------------------------
__global__ __launch_bounds__(256) void face_precomp(
    const float* __restrict__ obs_curr,
    const float* __restrict__ obs_next,
    const int* __restrict__ faces,
    float4* __restrict__ fcurr,
    float4* __restrict__ fnext) {
  int t = blockIdx.x * 256 + threadIdx.x;
  if (t >= B_ * F_) return;
  int b = t / F_;
  const float* oc = obs_curr + (size_t)b * M_ * 3;
  const float* on = obs_next + (size_t)b * M_ * 3;
  int i0 = faces[3 * (size_t)t + 0];
  int i1 = faces[3 * (size_t)t + 1];
  int i2 = faces[3 * (size_t)t + 2];

  float ax = oc[3*i0], ay = oc[3*i0+1], az = oc[3*i0+2];
  float bx = oc[3*i1], by = oc[3*i1+1], bz = oc[3*i1+2];
  float cx = oc[3*i2], cy = oc[3*i2+1], cz = oc[3*i2+2];
  float gx = (ax + bx + cx) / 3.0f;
  float gy = (ay + by + cy) / 3.0f;
  float gz = (az + bz + cz) / 3.0f;
  fcurr[t] = make_float4(gx, gy, gz, gx*gx + gy*gy + gz*gz);

  float nax = on[3*i0], nay = on[3*i0+1], naz = on[3*i0+2];
  float nbx = on[3*i1], nby = on[3*i1+1], nbz = on[3*i1+2];
  float ncx = on[3*i2], ncy = on[3*i2+1], ncz = on[3*i2+2];
  float hx = (nax + nbx + ncx) / 3.0f;
  float hy = (nay + nby + ncy) / 3.0f;
  float hz = (naz + nbz + ncz) / 3.0f;
  float e1x = nbx - nax, e1y = nby - nay, e1z = nbz - naz;
  float e2x = ncx - nax, e2y = ncy - nay, e2z = ncz - naz;
  float crx = e1y * e2z - e1z * e2y;
  float cry = e1z * e2x - e1x * e2z;
  float crz = e1x * e2y - e1y * e2x;
  float len = sqrtf(crx*crx + cry*cry + crz*crz);
  float inv = 1.0f / (len + 1e-12f);
  fnext[2 * (size_t)t + 0] = make_float4(hx, hy, hz, 0.0f);
  fnext[2 * (size_t)t + 1] = make_float4(crx*inv, cry*inv, crz*inv, 0.0f);
}

// ---------------------------------------------------------------------------
// Kernel B: min-ONLY pass. score = |fc|^2 - 2*c.fc (argmin-equiv to d2).
// 4 VALU/pair (3 fma + v_min_f32) — no index tracking; index recovered in
// the epilogue by rescanning the winning 128-face partition for the first
// bitwise-equal score (same fmaf chain => bitwise reproducible).
// __launch_bounds__(256,8): ~37 live VGPRs, cap 64 => 8 blocks/CU.
// ---------------------------------------------------------------------------
__global__ __launch_bounds__(256, 8) void knn_min(
    const float* __restrict__ cloth_curr,
    const float4* __restrict__ fcurr,
    float* __restrict__ pmin) {
  __shared__ float4 tile[TILE_];
  int bid = blockIdx.x;            // [0, 2048)
  int p = bid & (P_ - 1);          // face partition
  int chunk = (bid >> 7) & (NCHUNK_ - 1);
  int b = bid >> 10;               // batch

  int vbase = chunk * CHUNK_ + threadIdx.x;
  float m2x[VPT_], m2y[VPT_], m2z[VPT_];
#pragma unroll
  for (int v = 0; v < VPT_; ++v) {
    int i = vbase + v * 256;
    const float* cp = cloth_curr + ((size_t)b * N_ + i) * 3;
    m2x[v] = -2.0f * cp[0];
    m2y[v] = -2.0f * cp[1];
    m2z[v] = -2.0f * cp[2];
  }

  const float4* src = fcurr + (size_t)b * F_ + (size_t)p * TILE_;
  if (threadIdx.x < TILE_) tile[threadIdx.x] = src[threadIdx.x];
  __syncthreads();

  float best[VPT_];
#pragma unroll
  for (int v = 0; v < VPT_; ++v) best[v] = 3.4e38f;

#pragma unroll 4
  for (int f = 0; f < TILE_; ++f) {
    float4 fc = tile[f];
#pragma unroll
    for (int v = 0; v < VPT_; ++v) {
      float s = fmaf(m2x[v], fc.x, fmaf(m2y[v], fc.y, fmaf(m2z[v], fc.z, fc.w)));
      best[v] = fminf(best[v], s);
    }
  }

#pragma unroll
  for (int v = 0; v < VPT_; ++v)
    pmin[((size_t)(b * P_ + p)) * N_ + vbase + v * 256] = best[v];
}

// ---------------------------------------------------------------------------
// Kernel C: per (vertex,batch) thread — reduce P partition minima (strict <,
// ascending p => first winner), recover face index by first-equality rescan
// of the winning 128-face partition, then plane distance + interpenetration.
// Batch pair combined via lane^1 shuffle. 128 blocks.
// ---------------------------------------------------------------------------
__global__ __launch_bounds__(256) void epilogue(
    const float* __restrict__ cloth_curr,
    const float* __restrict__ cloth_next,
    const float4* __restrict__ fcurr,
    const float4* __restrict__ fnext,
    const float* __restrict__ pmin,
    const int* __restrict__ iter_num,
    float* __restrict__ out,
    float* __restrict__ block_sums) {
  int t = blockIdx.x * 256 + threadIdx.x;  // [0, 2*N)
  int i = t >> 1;                          // vertex
  int b = t & 1;                           // batch

  // weight ramp (double to match Python scalar math)
  int it = *iter_num;
  double itc = (double)(it - 50000);
  if (itc < 0.0) itc = 0.0;
  double prog = itc / 100000.0;
  if (prog > 1.0) prog = 1.0;
  float weight = (float)(1e-3 + (5e3 - 1e-3) * prog);
  float scale = weight * 0.5f;  // weight / B

  // partition-min scan (first strict winner)
  float best = 3.4e38f;
  int bp = 0;
#pragma unroll 8
  for (int p = 0; p < P_; ++p) {
    float s = pmin[((size_t)(b * P_ + p)) * N_ + i];
    bool m = s < best;
    best = m ? s : best;
    bp = m ? p : bp;
  }

  // index recovery: first bitwise-equal score in winning partition
  const float* cp = cloth_curr + ((size_t)b * N_ + i) * 3;
  float m2x = -2.0f * cp[0];
  float m2y = -2.0f * cp[1];
  float m2z = -2.0f * cp[2];
  const float4* fp = fcurr + (size_t)b * F_ + (size_t)bp * TILE_;
  int jwin = 0;
  int found = 0;
#pragma unroll 4
  for (int j = 0; j < TILE_; ++j) {
    float4 fc = fp[j];
    float s = fmaf(m2x, fc.x, fmaf(m2y, fc.y, fmaf(m2z, fc.z, fc.w)));
    bool eq = (s == best);
    jwin = (eq && !found) ? j : jwin;
    found = found | (int)eq;
  }
  int fidx = bp * TILE_ + jwin;

  float4 cent = fnext[2 * ((size_t)b * F_ + fidx) + 0];
  float4 nrm  = fnext[2 * ((size_t)b * F_ + fidx) + 1];
  const float* np2 = cloth_next + ((size_t)b * N_ + i) * 3;
  float dist = (np2[0] - cent.x) * nrm.x +
               (np2[1] - cent.y) * nrm.y +
               (np2[2] - cent.z) * nrm.z;
  float ip = fmaxf(1e-3f - dist, 0.0f);
  float acc = ip * ip * ip * scale;

  // combine the two batches (lanes 2k / 2k+1 hold b=0 / b=1 of vertex i)
  float pair = acc + __shfl_xor(acc, 1, 64);
  if (b == 0) out[1 + i] = pair;  // per_vert

  // block-level loss partial (deterministic: no atomics)
  float r = acc;
  for (int off = 32; off > 0; off >>= 1) r += __shfl_down(r, off, 64);
  __shared__ float wsum[4];
  int lane = threadIdx.x & 63;
  int w = threadIdx.x >> 6;
  if (lane == 0) wsum[w] = r;
  __syncthreads();
  if (threadIdx.x == 0)
    block_sums[blockIdx.x] = wsum[0] + wsum[1] + wsum[2] + wsum[3];
}

__global__ void final_sum(const float* __restrict__ block_sums,
                          float* __restrict__ out) {
  // 128 partials, 64 threads
  float v = block_sums[threadIdx.x] + block_sums[threadIdx.x + 64];
  for (int off = 32; off > 0; off >>= 1) v += __shfl_down(v, off, 64);
  if (threadIdx.x == 0) out[0] = v;
}

// ---------------------------------------------------------------------------
extern "C" void kernel_launch(void* const* d_in, const int* in_sizes, int n_in,
                              void* d_out, int out_size, void* d_ws, size_t ws_size,
                              hipStream_t stream) {
  const float* cloth_curr = (const float*)d_in[0];
  const float* cloth_next = (const float*)d_in[1];
  const float* obs_curr   = (const float*)d_in[2];
  const float* obs_next   = (const float*)d_in[3];
  const int*   faces      = (const int*)d_in[4];
  const int*   iter_num   = (const int*)d_in[5];
  float* out = (float*)d_out;

  // workspace layout (16B-aligned): fcurr 512K | fnext 1M | pmin 16.8M | sums
  char* w = (char*)d_ws;
  float4* fcurr = (float4*)(w);                    // B*F float4
  float4* fnext = (float4*)(w + 524288);           // B*F*2 float4
  float*  pmin  = (float*)(w + 1572864);           // B*P*N float = 16 MB
  float* block_sums = (float*)(w + 1572864 + (size_t)B_ * P_ * N_ * 4);

  face_precomp<<<(B_ * F_ + 255) / 256, 256, 0, stream>>>(
      obs_curr, obs_next, faces, fcurr, fnext);

  knn_min<<<B_ * NCHUNK_ * P_, 256, 0, stream>>>(cloth_curr, fcurr, pmin);

  epilogue<<<(2 * N_) / 256, 256, 0, stream>>>(
      cloth_curr, cloth_next, fcurr, fnext, pmin, iter_num, out, block_sums);

  final_sum<<<1, 64, 0, stream>>>(block_sums, out);
}